// Round 4
// baseline (255.085 us; speedup 1.0000x reference)
//
#include <hip/hip_runtime.h>

// MaskedContrastiveLoss: loss = 0.5*[mean_i(rowLSE_i - pos_i) + mean_j(colLSE_j - pos_j)]
// logits = (A @ B^T) * (1/0.07), A,B: [256, 65536] fp32 L2-normalized rows.
//
// R4: streaming no-LDS MFMA, wave-independent 32x32 subtiles (no cross-wave
// reduce -> zero LDS, low VGPR -> 4 waves/SIMD), C=64 K-chunks -> grid 1024
// (4 blocks/CU), XCD-swizzled so each chunk's 16 blocks share one XCD's L2.
// Reduce: coalesced row pass + colsum atomics + last-block finalize
// (kills R3's strided column pass). 2 dispatches total.

#define D_DIM 65536
#define B_DIM 256
#define C_CHUNKS 64
#define KC (D_DIM / C_CHUNKS)  // 1024 k per chunk

constexpr float TEMP = 1.0f / 0.07f;

typedef short short8 __attribute__((ext_vector_type(8)));
typedef float floatx4 __attribute__((ext_vector_type(4)));

__device__ inline unsigned fbits(float f) { return __builtin_bit_cast(unsigned, f); }

// two f32 -> packed bf16 pair (round-to-nearest, ties-up): 2 adds + 1 v_perm
__device__ inline unsigned pkbf(float lo, float hi) {
  return __builtin_amdgcn_perm(fbits(hi) + 0x8000u, fbits(lo) + 0x8000u, 0x07060302);
}

__device__ inline short8 cvt_frag(float4 lo, float4 hi) {
  union { unsigned u[4]; short8 s; } r;
  r.u[0] = pkbf(lo.x, lo.y);
  r.u[1] = pkbf(lo.z, lo.w);
  r.u[2] = pkbf(hi.x, hi.y);
  r.u[3] = pkbf(hi.z, hi.w);
  return r.s;
}

// grid = 16 tiles * 64 chunks = 1024 blocks, 256 threads (4 waves).
// bid = tile*64 + chunk: the 16 blocks of chunk c all have bid%8 == c%8
// -> same XCD -> chunk's 2 MB working set served from that XCD's 4 MB L2.
// Each wave owns a 32x32 quadrant of the block's 64x64 tile, full chunk K.
__global__ __launch_bounds__(256, 4) void gemm_stream(
    const float* __restrict__ A, const float* __restrict__ Bm,
    float* __restrict__ partials, float* __restrict__ colsum,
    float* __restrict__ out, unsigned* __restrict__ counter) {
  const int bid = blockIdx.x;
  const int t = threadIdx.x;
  if (bid == 0) {  // zero reduce-kernel accumulators; stream order makes this safe
    colsum[t] = 0.f;
    if (t == 0) { *out = 0.f; *counter = 0u; }
  }

  const int chunk = bid & (C_CHUNKS - 1);
  const int tile = bid >> 6;  // 0..15
  const int mt = (tile & 3) * 64;
  const int nt = (tile >> 2) * 64;

  const int lane = t & 63;
  const int w = t >> 6;
  const int wm = mt + (w & 1) * 32;   // wave's 32x32 quadrant
  const int wn = nt + (w >> 1) * 32;
  const int r16 = lane & 15;
  const int q = lane >> 4;            // k-offset quad

  const size_t kb = (size_t)chunk * KC + (size_t)q * 8;
  const float* pa0 = A + (size_t)(wm + r16) * D_DIM + kb;
  const float* pa1 = pa0 + (size_t)16 * D_DIM;
  const float* pb0 = Bm + (size_t)(wn + r16) * D_DIM + kb;
  const float* pb1 = pb0 + (size_t)16 * D_DIM;

  floatx4 acc00 = (floatx4)0.f, acc01 = (floatx4)0.f;
  floatx4 acc10 = (floatx4)0.f, acc11 = (floatx4)0.f;

  float4 x[8], y[8];

#define LOADSET(d, off)                                  \
  {                                                      \
    d[0] = *(const float4*)(pa0 + (off));                \
    d[1] = *(const float4*)(pa0 + (off) + 4);            \
    d[2] = *(const float4*)(pa1 + (off));                \
    d[3] = *(const float4*)(pa1 + (off) + 4);            \
    d[4] = *(const float4*)(pb0 + (off));                \
    d[5] = *(const float4*)(pb0 + (off) + 4);            \
    d[6] = *(const float4*)(pb1 + (off));                \
    d[7] = *(const float4*)(pb1 + (off) + 4);            \
  }

#define COMPUTESET(d)                                                       \
  {                                                                         \
    short8 a0 = cvt_frag(d[0], d[1]);                                       \
    short8 a1 = cvt_frag(d[2], d[3]);                                       \
    short8 b0 = cvt_frag(d[4], d[5]);                                       \
    short8 b1 = cvt_frag(d[6], d[7]);                                       \
    acc00 = __builtin_amdgcn_mfma_f32_16x16x32_bf16(a0, b0, acc00, 0, 0, 0);\
    acc01 = __builtin_amdgcn_mfma_f32_16x16x32_bf16(a0, b1, acc01, 0, 0, 0);\
    acc10 = __builtin_amdgcn_mfma_f32_16x16x32_bf16(a1, b0, acc10, 0, 0, 0);\
    acc11 = __builtin_amdgcn_mfma_f32_16x16x32_bf16(a1, b1, acc11, 0, 0, 0);\
  }

  LOADSET(x, 0)
#pragma unroll 1
  for (int g = 0; g < KC / 64; ++g) {  // 16 iters, 2 K-steps each, 2-deep prefetch
    LOADSET(y, g * 64 + 32)
    COMPUTESET(x)
    if (g + 1 < KC / 64) LOADSET(x, g * 64 + 64)
    COMPUTESET(y)
  }
#undef LOADSET
#undef COMPUTESET

  // epilogue: C/D layout col = lane&15, row = q*4 + r (per 16x16 block)
  float* op = partials + (size_t)chunk * (B_DIM * B_DIM);
  const floatx4* accs[4] = {&acc00, &acc01, &acc10, &acc11};
#pragma unroll
  for (int fa = 0; fa < 2; ++fa)
#pragma unroll
    for (int fb = 0; fb < 2; ++fb) {
      const floatx4 a = *accs[fa * 2 + fb];
      const int col = wn + fb * 16 + r16;
#pragma unroll
      for (int r = 0; r < 4; ++r)
        op[(size_t)(wm + fa * 16 + q * 4 + r) * B_DIM + col] = a[r];
    }
}

// block i: sum chunks for row i (coalesced), rowLSE_i + pos_i -> out;
// exp values atomicAdd'ed into colsum[j]; last block finishes col-LSE sum.
__global__ __launch_bounds__(256, 2) void reduce_all(
    const float* __restrict__ partials, float* __restrict__ colsum,
    float* __restrict__ out, unsigned* __restrict__ counter) {
  const int i = blockIdx.x;
  const int j = threadIdx.x;

  float s = 0.f;
  const float* p = partials + (size_t)i * B_DIM + j;
#pragma unroll
  for (int c = 0; c < C_CHUNKS; ++c) s += p[(size_t)c * (B_DIM * B_DIM)];
  const float lg = s * TEMP;

  __shared__ float posv;
  if (j == i) posv = lg;

  // |logit| <= TEMP (Cauchy-Schwarz, unit rows): exp safe without max-shift
  const float e = expf(lg);
  atomicAdd(&colsum[j], e);

  float r = e;
#pragma unroll
  for (int off = 32; off > 0; off >>= 1) r += __shfl_down(r, off);
  __shared__ float wsum[4];
  if ((j & 63) == 0) wsum[j >> 6] = r;
  __threadfence();  // publish colsum adds before counter increment
  __syncthreads();

  __shared__ bool last;
  if (j == 0) {
    const float rowsum = wsum[0] + wsum[1] + wsum[2] + wsum[3];
    atomicAdd(out, (logf(rowsum) - 2.f * posv) * (0.5f / 256.f));
    last = (atomicAdd(counter, 1u) == B_DIM - 1);
  }
  __syncthreads();

  if (last) {
    __threadfence();  // acquire: all blocks' colsum adds are visible
    float cl = logf(colsum[j]);
#pragma unroll
    for (int off = 32; off > 0; off >>= 1) cl += __shfl_down(cl, off);
    if ((j & 63) == 0) wsum[j >> 6] = cl;
    __syncthreads();
    if (j == 0)
      atomicAdd(out, (wsum[0] + wsum[1] + wsum[2] + wsum[3]) * (0.5f / 256.f));
  }
}

extern "C" void kernel_launch(void* const* d_in, const int* in_sizes, int n_in,
                              void* d_out, int out_size, void* d_ws, size_t ws_size,
                              hipStream_t stream) {
  (void)in_sizes; (void)n_in; (void)out_size; (void)ws_size;
  const float* A = (const float*)d_in[0];
  const float* Bm = (const float*)d_in[1];
  float* out = (float*)d_out;

  // ws: [partials: 64*256*256 f32 = 16 MB][colsum: 256 f32][counter: 1 u32]
  float* partials = (float*)d_ws;
  float* colsum = partials + (size_t)C_CHUNKS * B_DIM * B_DIM;
  unsigned* counter = (unsigned*)(colsum + B_DIM);

  gemm_stream<<<16 * C_CHUNKS, 256, 0, stream>>>(A, Bm, partials, colsum, out, counter);
  reduce_all<<<B_DIM, B_DIM, 0, stream>>>(partials, colsum, out, counter);
}

// Round 5
// 176.924 us; speedup vs baseline: 1.4418x; 1.4418x over previous
//
#include <hip/hip_runtime.h>

// MaskedContrastiveLoss: loss = 0.5*[mean_i(rowLSE_i - pos_i) + mean_j(colLSE_j - pos_j)]
// logits = (A @ B^T) * (1/0.07), A,B: [256, 65536] fp32 L2-normalized rows.
//
// R5: R1's proven structure (128x128 tiles, C=128 chunks, consecutive-bid
// chunk grouping -> compulsory 131 MB fetch, perfectly coalesced staging)
// + 3-stage software pipeline: TWO register buffer sets, global loads issued
// TWO stages ahead, ONE barrier per stage (LDS double-buffered). The R1
// store-side vmcnt stall (loads only 1 stage deep) was the 38%-of-peak cap.
// launch_bounds(256,2): 256-reg budget so the compiler keeps both prefetch
// sets live (R4 showed tight budgets make it serialize the loads).

#define D_DIM 65536
#define B_DIM 256
#define LDK 72  // padded LDS row stride (shorts); 2-way bank aliasing only (free)

constexpr float TEMP = 1.0f / 0.07f;

typedef short short8 __attribute__((ext_vector_type(8)));
typedef float floatx4 __attribute__((ext_vector_type(4)));

__device__ inline unsigned fbits(float f) { return __builtin_bit_cast(unsigned, f); }

// two f32 -> packed bf16 (round-to-nearest, ties-up): 2 adds + 1 v_perm
__device__ inline unsigned pkbf(float lo, float hi) {
  return __builtin_amdgcn_perm(fbits(hi) + 0x8000u, fbits(lo) + 0x8000u, 0x07060302);
}

__device__ inline void st_bf16x4(unsigned short* dst, float4 v) {
  uint2 u;
  u.x = pkbf(v.x, v.y);
  u.y = pkbf(v.z, v.w);
  *(uint2*)dst = u;
}

// grid = 4*C blocks, 256 threads (4 waves). bid>>2 = chunk: the 4 blocks of a
// chunk are CONSECUTIVE bids -> co-launched -> tile redundancy absorbed by LLC.
__global__ __launch_bounds__(256, 2) void gemm_splitk(
    const float* __restrict__ A, const float* __restrict__ Bm,
    float* __restrict__ partials, float* __restrict__ colsum,
    float* __restrict__ out, unsigned* __restrict__ counter, int Kc) {
  const int bid = blockIdx.x;
  const int t = threadIdx.x;
  if (bid == 0) {  // zero reduce accumulators (ws is poisoned each launch)
    colsum[t] = 0.f;
    if (t == 0) { *out = 0.f; *counter = 0u; }
  }

  const int mt = (bid & 1) * 128;
  const int nt = ((bid >> 1) & 1) * 128;
  const int chunk = bid >> 2;
  const size_t k0 = (size_t)chunk * (size_t)Kc;

  __shared__ unsigned short As[2][128][LDK];  // 72 KB total -> 2 blocks/CU
  __shared__ unsigned short Bs[2][128][LDK];

  const int lane = t & 63;
  const int w = t >> 6;
  const int wm = (w & 1) * 64;
  const int wn = (w >> 1) * 64;
  const int lane15 = lane & 15;
  const int laneq = lane >> 4;

  // staging: 16 threads cover one row's 64 floats (256 B, fully coalesced)
  const int lr = t >> 4;
  const int lc = (t & 15) * 4;

  const float* Abase = A + (size_t)(mt + lr) * D_DIM + k0 + lc;
  const float* Bbase = Bm + (size_t)(nt + lr) * D_DIM + k0 + lc;

  floatx4 acc[4][4];
#pragma unroll
  for (int mb = 0; mb < 4; ++mb)
#pragma unroll
    for (int nb = 0; nb < 4; ++nb) acc[mb][nb] = (floatx4)0.f;

  float4 ra0[8], rb0[8], ra1[8], rb1[8];  // two prefetch sets (2 stages deep)
  const int nst = Kc >> 6;                // stages of BK=64; nst is even (8/16)

#pragma unroll
  for (int p = 0; p < 8; ++p) {
    ra0[p] = *(const float4*)(Abase + (size_t)p * 16 * D_DIM);
    rb0[p] = *(const float4*)(Bbase + (size_t)p * 16 * D_DIM);
  }
#pragma unroll
  for (int p = 0; p < 8; ++p) {
    ra1[p] = *(const float4*)(Abase + (size_t)p * 16 * D_DIM + 64);
    rb1[p] = *(const float4*)(Bbase + (size_t)p * 16 * D_DIM + 64);
  }

#define STAGE(RA, RB, BUF, S)                                                  \
  {                                                                            \
    _Pragma("unroll") for (int p = 0; p < 8; ++p) {                            \
      st_bf16x4(&As[BUF][lr + p * 16][lc], RA[p]);                             \
      st_bf16x4(&Bs[BUF][lr + p * 16][lc], RB[p]);                             \
    }                                                                          \
    __syncthreads(); /* single barrier: dbuf makes write(s+1) vs read(s) safe*/\
    if ((S) + 2 < nst) {                                                       \
      const float* Ap = Abase + (size_t)((S) + 2) * 64;                        \
      const float* Bp = Bbase + (size_t)((S) + 2) * 64;                        \
      _Pragma("unroll") for (int p = 0; p < 8; ++p) {                          \
        RA[p] = *(const float4*)(Ap + (size_t)p * 16 * D_DIM);                 \
        RB[p] = *(const float4*)(Bp + (size_t)p * 16 * D_DIM);                 \
      }                                                                        \
    }                                                                          \
    _Pragma("unroll") for (int ks = 0; ks < 64; ks += 32) {                    \
      const int ko = ks + laneq * 8;                                           \
      short8 af[4], bf[4];                                                     \
      _Pragma("unroll") for (int mb = 0; mb < 4; ++mb)                         \
          af[mb] = *(const short8*)&As[BUF][wm + mb * 16 + lane15][ko];        \
      _Pragma("unroll") for (int nb = 0; nb < 4; ++nb)                         \
          bf[nb] = *(const short8*)&Bs[BUF][wn + nb * 16 + lane15][ko];        \
      _Pragma("unroll") for (int mb = 0; mb < 4; ++mb)                         \
          _Pragma("unroll") for (int nb = 0; nb < 4; ++nb)                     \
              acc[mb][nb] = __builtin_amdgcn_mfma_f32_16x16x32_bf16(           \
                  af[mb], bf[nb], acc[mb][nb], 0, 0, 0);                       \
    }                                                                          \
  }

#pragma unroll 1
  for (int s = 0; s < nst; s += 2) {  // unroll-by-2 keeps buffer sets static
    STAGE(ra0, rb0, 0, s)
    STAGE(ra1, rb1, 1, s + 1)
  }
#undef STAGE

  // epilogue: C/D layout col = lane&15, row = quad*4 + r
  float* outp = partials + (size_t)chunk * (B_DIM * B_DIM);
#pragma unroll
  for (int mb = 0; mb < 4; ++mb) {
    const int gi0 = mt + wm + mb * 16 + laneq * 4;
#pragma unroll
    for (int nb = 0; nb < 4; ++nb) {
      const int gj = nt + wn + nb * 16 + lane15;
#pragma unroll
      for (int r = 0; r < 4; ++r)
        outp[(size_t)(gi0 + r) * B_DIM + gj] = acc[mb][nb][r];
    }
  }
}

// block i: sum chunks for row i (coalesced), rowLSE_i + pos_i -> out;
// exp values atomicAdd into colsum[j]; last block finishes the column LSEs.
__global__ __launch_bounds__(256, 2) void reduce_all(
    const float* __restrict__ partials, float* __restrict__ colsum,
    float* __restrict__ out, unsigned* __restrict__ counter, int C) {
  const int i = blockIdx.x;
  const int j = threadIdx.x;

  float s = 0.f;
  const float* p = partials + (size_t)i * B_DIM + j;
#pragma unroll 8
  for (int c = 0; c < C; ++c) s += p[(size_t)c * (B_DIM * B_DIM)];
  const float lg = s * TEMP;

  __shared__ float posv;
  if (j == i) posv = lg;

  // |logit| <= TEMP (Cauchy-Schwarz, unit rows): exp safe without max-shift
  const float e = expf(lg);
  atomicAdd(&colsum[j], e);

  float r = e;
#pragma unroll
  for (int off = 32; off > 0; off >>= 1) r += __shfl_down(r, off);
  __shared__ float wsum[4];
  if ((j & 63) == 0) wsum[j >> 6] = r;
  __threadfence();  // publish colsum adds before counter increment
  __syncthreads();

  __shared__ bool last;
  if (j == 0) {
    const float rowsum = wsum[0] + wsum[1] + wsum[2] + wsum[3];
    atomicAdd(out, (logf(rowsum) - 2.f * posv) * (0.5f / 256.f));
    last = (atomicAdd(counter, 1u) == B_DIM - 1);
  }
  __syncthreads();

  if (last) {
    __threadfence();  // acquire: all blocks' colsum adds visible
    float cl = logf(colsum[j]);
#pragma unroll
    for (int off = 32; off > 0; off >>= 1) cl += __shfl_down(cl, off);
    if ((j & 63) == 0) wsum[j >> 6] = cl;
    __syncthreads();
    if (j == 0)
      atomicAdd(out, (wsum[0] + wsum[1] + wsum[2] + wsum[3]) * (0.5f / 256.f));
  }
}

extern "C" void kernel_launch(void* const* d_in, const int* in_sizes, int n_in,
                              void* d_out, int out_size, void* d_ws, size_t ws_size,
                              hipStream_t stream) {
  (void)in_sizes; (void)n_in; (void)out_size;
  const float* A = (const float*)d_in[0];
  const float* Bm = (const float*)d_in[1];
  float* out = (float*)d_out;

  // ws: [partials: C*256*256 f32][colsum: 256 f32][counter: 1 u32]
  const size_t per = (size_t)B_DIM * B_DIM * sizeof(float);
  int C = 128;
  while (C > 4 && (size_t)C * per + 2048 > ws_size) C >>= 1;
  const int Kc = D_DIM / C;

  float* partials = (float*)d_ws;
  float* colsum = partials + (size_t)C * B_DIM * B_DIM;
  unsigned* counter = (unsigned*)(colsum + B_DIM);

  gemm_splitk<<<4 * C, 256, 0, stream>>>(A, Bm, partials, colsum, out, counter, Kc);
  reduce_all<<<B_DIM, B_DIM, 0, stream>>>(partials, colsum, out, counter, C);
}